// Round 5
// baseline (176.080 us; speedup 1.0000x reference)
//
#include <hip/hip_runtime.h>
#include <hip/hip_bf16.h>
#include <stdint.h>

// SpaceLoss2, round 5: two kernels, no init/prep, no cooperative sync.
//   sim = ftr @ ftr^T via fp16 MFMA (fp16 dot err sd ~0.016 vs argmin
//   1st-2nd order-stat gap ~4.3 -> argmin-safe). fp32->fp16 conversion is
//   done in-kernel during LDS staging (ftr is 4 MB, L2/L3-resident; the
//   re-conversion VALU is free in this MFMA-light kernel).
//   Lower-triangle 128x128 tiles only (528 blocks). Per-(row,tile) masked
//   argmin partials are WRITTEN (not atomicMin'd) to P[row][slot], slot=bx
//   for the row-pass and slot=by for the col-pass; col-pass skipped on
//   diagonal tiles => every slot [0,32) written exactly once, so the
//   0xAA-poisoned scratch needs no init. Key = (ordered-float-bits<<32)|col
//   preserves jnp.argmin min-value-then-min-index tie-break under u64 min.
//   Loss kernel min-reduces 32 keys/row and computes the relu'd distances.

typedef _Float16 f16;
typedef _Float16 f16x8 __attribute__((ext_vector_type(8)));
typedef float f32x4 __attribute__((ext_vector_type(4)));
typedef unsigned long long u64;

__device__ __forceinline__ u64 float_key(float x) {
    unsigned int u = __float_as_uint(x);
    u = (u & 0x80000000u) ? ~u : (u | 0x80000000u);
    return (u64)u;
}

__device__ __forceinline__ u64 shfl_xor_u64(u64 v, int mask) {
    unsigned int lo = (unsigned int)(v & 0xFFFFFFFFULL);
    unsigned int hi = (unsigned int)(v >> 32);
    lo = __shfl_xor(lo, mask, 64);
    hi = __shfl_xor(hi, mask, 64);
    return ((u64)hi << 32) | (u64)lo;
}

// 128x128 triangle tile, BK=64, 4 waves x (4x4 frags of 16x16x32 f16 MFMA).
// LDS [128][64] f16, 16B-chunk XOR-swizzled (chunk c of row r holds k-chunk
// c^(r&7)) -> stride-128B ds_reads are conflict-free.
__global__ __launch_bounds__(256, 3) void sim_kernel(
    const float* __restrict__ ftr, const int* __restrict__ label,
    u64* __restrict__ P, float* __restrict__ out, int B, int D)
{
    __shared__ __align__(16) f16 sA[128 * 64];
    __shared__ __align__(16) f16 sB[128 * 64];
    __shared__ int sLabR[128];
    __shared__ int sLabC[128];
    __shared__ u64 sRedR[2][128];
    __shared__ u64 sRedC[2][128];

    // linear block id -> (bx <= by) lower-triangle coords
    int bi = blockIdx.x;
    int by = (int)((sqrtf(8.0f * (float)bi + 1.0f) - 1.0f) * 0.5f);
    while ((by + 1) * (by + 2) / 2 <= bi) ++by;
    while (by * (by + 1) / 2 > bi) --by;
    const int bx = bi - by * (by + 1) / 2;
    const bool diag = (bx == by);

    const int row0 = by * 128;
    const int col0 = bx * 128;

    const int tid  = threadIdx.x;
    const int lane = tid & 63;
    const int w    = tid >> 6;

    if (tid == 0)   // all blocks store the same value: benign race, zeroes out
        __hip_atomic_store(out, 0.0f, __ATOMIC_RELAXED, __HIP_MEMORY_SCOPE_AGENT);
    if (tid < 128) sLabR[tid] = label[row0 + tid];
    else           sLabC[tid - 128] = label[col0 + (tid - 128)];

    // staging: thread handles rows (tid>>3)+{0,32,64,96}, k-chunk tid&7.
    const int srow = tid >> 3;
    const int skc  = tid & 7;

    f32x4 acc[4][4];
#pragma unroll
    for (int i = 0; i < 4; ++i)
#pragma unroll
        for (int j = 0; j < 4; ++j) acc[i][j] = (f32x4){0.f, 0.f, 0.f, 0.f};

    const int wr = (w >> 1) * 64;
    const int wc = (w & 1) * 64;
    const int qk = lane >> 4;
    const int ln = lane & 15;

    for (int k0 = 0; k0 < D; k0 += 64) {
        __syncthreads();
#pragma unroll
        for (int t = 0; t < 4; ++t) {
            const int r = srow + t * 32;
            const int ldsoff = r * 64 + (((skc ^ (r & 7)) << 3));
            {
                const float* g = ftr + (size_t)(row0 + r) * D + k0 + skc * 8;
                float4 a0 = *(const float4*)g;
                float4 a1 = *(const float4*)(g + 4);
                f16x8 h = { (f16)a0.x, (f16)a0.y, (f16)a0.z, (f16)a0.w,
                            (f16)a1.x, (f16)a1.y, (f16)a1.z, (f16)a1.w };
                *(f16x8*)&sA[ldsoff] = h;
            }
            {
                const float* g = ftr + (size_t)(col0 + r) * D + k0 + skc * 8;
                float4 b0 = *(const float4*)g;
                float4 b1 = *(const float4*)(g + 4);
                f16x8 h = { (f16)b0.x, (f16)b0.y, (f16)b0.z, (f16)b0.w,
                            (f16)b1.x, (f16)b1.y, (f16)b1.z, (f16)b1.w };
                *(f16x8*)&sB[ldsoff] = h;
            }
        }
        __syncthreads();

#pragma unroll
        for (int kk = 0; kk < 2; ++kk) {
            const int q  = kk * 4 + qk;
            const int cs = ((q ^ (ln & 7)) << 3);
            f16x8 aF[4], bF[4];
#pragma unroll
            for (int f = 0; f < 4; ++f) {
                aF[f] = __builtin_bit_cast(f16x8, *(const uint4*)&sA[(wr + f * 16 + ln) * 64 + cs]);
                bF[f] = __builtin_bit_cast(f16x8, *(const uint4*)&sB[(wc + f * 16 + ln) * 64 + cs]);
            }
#pragma unroll
            for (int i = 0; i < 4; ++i)
#pragma unroll
                for (int j = 0; j < 4; ++j)
                    acc[i][j] = __builtin_amdgcn_mfma_f32_16x16x32_f16(
                        aF[i], bF[j], acc[i][j], 0, 0, 0);
        }
    }

    // row-wise argmin -> LDS (C/D 16x16 layout: col = lane&15, row = quad*4+reg)
#pragma unroll
    for (int i = 0; i < 4; ++i) {
#pragma unroll
        for (int reg = 0; reg < 4; ++reg) {
            const int lr  = wr + i * 16 + qk * 4 + reg;
            const int lab = sLabR[lr];
            u64 bl = ~0ULL;
#pragma unroll
            for (int j = 0; j < 4; ++j) {
                const int c = col0 + wc + j * 16 + ln;
                u64 key = (float_key(acc[i][j][reg]) << 32) | (unsigned int)c;
                if (c != lab && key < bl) bl = key;
            }
#pragma unroll
            for (int off = 1; off < 16; off <<= 1) {
                u64 o = shfl_xor_u64(bl, off);
                if (o < bl) bl = o;
            }
            if (ln == 0) sRedR[w & 1][lr] = bl;
        }
    }

    // col-wise argmin -> LDS (skip on diagonal: duplicate of row-pass)
    if (!diag) {
#pragma unroll
        for (int j = 0; j < 4; ++j) {
            const int cl  = wc + j * 16 + ln;
            const int lab = sLabC[cl];
            u64 bl = ~0ULL;
#pragma unroll
            for (int i = 0; i < 4; ++i) {
#pragma unroll
                for (int reg = 0; reg < 4; ++reg) {
                    const int rg = row0 + wr + i * 16 + qk * 4 + reg;
                    u64 key = (float_key(acc[i][j][reg]) << 32) | (unsigned int)rg;
                    if (rg != lab && key < bl) bl = key;
                }
            }
            u64 o = shfl_xor_u64(bl, 16); if (o < bl) bl = o;
            o     = shfl_xor_u64(bl, 32); if (o < bl) bl = o;
            if (qk == 0) sRedC[w >> 1][cl] = bl;
        }
    }

    __syncthreads();
    // single write per (row, slot): slot bx for rows, slot by for cols
    if (tid < 128) {
        u64 a = sRedR[0][tid], b = sRedR[1][tid];
        P[(size_t)(row0 + tid) * 32 + bx] = (a < b ? a : b);
    } else if (!diag) {
        const int c = tid - 128;
        u64 a = sRedC[0][c], b = sRedC[1][c];
        P[(size_t)(col0 + c) * 32 + by] = (a < b ? a : b);
    }
}

// one wave per row: min-reduce 32 partial keys, then distances + relu + mean
__global__ __launch_bounds__(256) void loss_kernel(
    const float* __restrict__ ftr, const float* __restrict__ proto,
    const int* __restrict__ label, const u64* __restrict__ P,
    float* __restrict__ out, int B, int D, float inv_b)
{
    const int gid  = blockIdx.x * blockDim.x + threadIdx.x;
    const int row  = gid >> 6;
    const int lane = gid & 63;
    if (row >= B) return;

    u64 bl = (lane < 32) ? P[(size_t)row * 32 + lane] : ~0ULL;
#pragma unroll
    for (int off = 32; off >= 1; off >>= 1) {
        u64 o = shfl_xor_u64(bl, off);
        if (o < bl) bl = o;
    }
    const int neg = (int)(unsigned int)(bl & 0xFFFFFFFFULL);
    const int lab = label[row];

    float pd = 0.0f, nd = 0.0f;
    for (int d = lane * 4; d < D; d += 256) {
        float4 f = *(const float4*)(ftr   + (size_t)row * D + d);
        float4 y = *(const float4*)(proto + (size_t)lab * D + d);
        float4 n = *(const float4*)(ftr   + (size_t)neg * D + d);
        float dx = f.x - y.x, dy = f.y - y.y, dz = f.z - y.z, dw = f.w - y.w;
        pd += dx * dx + dy * dy + dz * dz + dw * dw;
        dx = f.x - n.x; dy = f.y - n.y; dz = f.z - n.z; dw = f.w - n.w;
        nd += dx * dx + dy * dy + dz * dz + dw * dw;
    }
#pragma unroll
    for (int off = 32; off >= 1; off >>= 1) {
        pd += __shfl_xor(pd, off, 64);
        nd += __shfl_xor(nd, off, 64);
    }
    if (lane == 0) {
        float l = pd - nd + 0.5f;
        if (l > 0.0f) atomicAdd(out, l * inv_b);
    }
}

extern "C" void kernel_launch(void* const* d_in, const int* in_sizes, int n_in,
                              void* d_out, int out_size, void* d_ws, size_t ws_size,
                              hipStream_t stream) {
    const float* ftr   = (const float*)d_in[0];
    // d_in[1] = teachor_ftr unused by the reference
    const float* proto = (const float*)d_in[2];
    const int*   label = (const int*)d_in[3];

    const int B = in_sizes[3];
    const int D = in_sizes[0] / B;      // 256

    u64* P = (u64*)d_ws;                // P[B][32] partial argmin keys (1 MB)
    float* out = (float*)d_out;

    const int nb   = B / 128;
    const int ntri = nb * (nb + 1) / 2;

    sim_kernel<<<ntri, 256, 0, stream>>>(ftr, label, P, out, B, D);
    loss_kernel<<<(B * 64 + 255) / 256, 256, 0, stream>>>(ftr, proto, label, P, out, B, D,
                                                          1.0f / (float)B);
}

// Round 7
// 155.555 us; speedup vs baseline: 1.1319x; 1.1319x over previous
//
#include <hip/hip_runtime.h>
#include <hip/hip_bf16.h>
#include <stdint.h>

// SpaceLoss2, round 7 = R6 with the loss-kernel reduction bug fixed.
// (R6 crashed: lanes 32..63 never received the reduced min -> neg=0xFFFFFFFF
//  -> OOB read. Now the half-wave merge is a real min, all lanes valid.)
//
// Structure (best known): prep (fp32->fp16, zero out) -> sim (lower-triangle
// 128x128 fp16 MFMA tiles + fused masked argmin, exactly-once P-table
// writes) -> loss (min-reduce 32 partials/row, distances, relu, mean).
// Key = (ordered-float-bits<<32)|col preserves jnp.argmin tie-break.

typedef _Float16 f16;
typedef _Float16 f16x4 __attribute__((ext_vector_type(4)));
typedef _Float16 f16x8 __attribute__((ext_vector_type(8)));
typedef float f32x4 __attribute__((ext_vector_type(4)));
typedef unsigned long long u64;

__device__ __forceinline__ u64 float_key(float x) {
    unsigned int u = __float_as_uint(x);
    u = (u & 0x80000000u) ? ~u : (u | 0x80000000u);
    return (u64)u;
}

__device__ __forceinline__ u64 shfl_xor_u64(u64 v, int mask) {
    unsigned int lo = (unsigned int)(v & 0xFFFFFFFFULL);
    unsigned int hi = (unsigned int)(v >> 32);
    lo = __shfl_xor(lo, mask, 64);
    hi = __shfl_xor(hi, mask, 64);
    return ((u64)hi << 32) | (u64)lo;
}

__device__ __forceinline__ void async_load16(const void* g, void* lds) {
    __builtin_amdgcn_global_load_lds(
        (__attribute__((address_space(1))) void*)(g),
        (__attribute__((address_space(3))) void*)(lds),
        16, 0, 0);
}

// fp32 ftr -> fp16 F; zero out. (P needs no init: written exactly once.)
__global__ __launch_bounds__(256) void prep_kernel(
    const float* __restrict__ x, f16* __restrict__ F, float* __restrict__ out,
    int B, int D)
{
    int gid = blockIdx.x * blockDim.x + threadIdx.x;
    int n4 = (B * D) >> 2;
    if (gid < n4) {
        float4 v = ((const float4*)x)[gid];
        f16x4 h = { (f16)v.x, (f16)v.y, (f16)v.z, (f16)v.w };
        ((f16x4*)F)[gid] = h;
    }
    if (gid == 0) out[0] = 0.0f;
}

// Lower-triangle tiles: 128x128, BK=64, 4 waves x (4x4 frags, 16x16x32 f16
// MFMA). LDS [128][64] f16, 16B-chunk XOR-swizzled (chunk c of row r holds
// k-chunk c^(r&7)): conflict-free ds_read_b128 while staying contiguous for
// global_load_lds (wave-uniform base + lane*16).
__global__ __launch_bounds__(256, 3) void sim_kernel(
    const f16* __restrict__ F, const int* __restrict__ label,
    u64* __restrict__ P, int B, int K)
{
    __shared__ __align__(16) f16 sA[128 * 64];
    __shared__ __align__(16) f16 sB[128 * 64];
    __shared__ int sLabR[128];
    __shared__ int sLabC[128];
    __shared__ u64 sRedR[2][128];
    __shared__ u64 sRedC[2][128];

    // linear block id -> (bx <= by) lower-triangle coords
    int bi = blockIdx.x;
    int by = (int)((sqrtf(8.0f * (float)bi + 1.0f) - 1.0f) * 0.5f);
    while ((by + 1) * (by + 2) / 2 <= bi) ++by;
    while (by * (by + 1) / 2 > bi) --by;
    const int bx = bi - by * (by + 1) / 2;
    const bool diag = (bx == by);

    const int row0 = by * 128;
    const int col0 = bx * 128;

    const int tid  = threadIdx.x;
    const int lane = tid & 63;
    const int w    = tid >> 6;

    if (tid < 128) sLabR[tid] = label[row0 + tid];
    else           sLabC[tid - 128] = label[col0 + (tid - 128)];

    // staging: wave w covers rows w*32..w*32+31 (4 instrs x 8 rows x 8 chunks)
    const int srow   = w * 32 + (lane >> 3);
    const int schunk = ((lane & 7) ^ (lane >> 3)) << 3;     // f16 elements
    const f16* gA = F + (size_t)(row0 + srow) * K + schunk;
    const f16* gB = F + (size_t)(col0 + srow) * K + schunk;
    f16* lA0 = sA + (w * 32) * 64;
    f16* lB0 = sB + (w * 32) * 64;

    f32x4 acc[4][4];
#pragma unroll
    for (int i = 0; i < 4; ++i)
#pragma unroll
        for (int j = 0; j < 4; ++j) acc[i][j] = (f32x4){0.f, 0.f, 0.f, 0.f};

    const int wr = (w >> 1) * 64;
    const int wc = (w & 1) * 64;
    const int qk = lane >> 4;
    const int ln = lane & 15;

    for (int k0 = 0; k0 < K; k0 += 64) {
        __syncthreads();
#pragma unroll
        for (int t = 0; t < 4; ++t) {
            async_load16(gA + (size_t)(t * 8) * K + k0, lA0 + t * 8 * 64);
            async_load16(gB + (size_t)(t * 8) * K + k0, lB0 + t * 8 * 64);
        }
        __syncthreads();

#pragma unroll
        for (int kk = 0; kk < 2; ++kk) {
            const int q  = kk * 4 + qk;
            const int cs = ((q ^ (ln & 7)) << 3);
            f16x8 aF[4], bF[4];
#pragma unroll
            for (int f = 0; f < 4; ++f) {
                aF[f] = __builtin_bit_cast(f16x8, *(const uint4*)&sA[(wr + f * 16 + ln) * 64 + cs]);
                bF[f] = __builtin_bit_cast(f16x8, *(const uint4*)&sB[(wc + f * 16 + ln) * 64 + cs]);
            }
#pragma unroll
            for (int i = 0; i < 4; ++i)
#pragma unroll
                for (int j = 0; j < 4; ++j)
                    acc[i][j] = __builtin_amdgcn_mfma_f32_16x16x32_f16(
                        aF[i], bF[j], acc[i][j], 0, 0, 0);
        }
    }

    // row-wise argmin -> LDS (C/D 16x16: col = lane&15, row = quad*4 + reg)
#pragma unroll
    for (int i = 0; i < 4; ++i) {
#pragma unroll
        for (int reg = 0; reg < 4; ++reg) {
            const int lr  = wr + i * 16 + qk * 4 + reg;
            const int lab = sLabR[lr];
            u64 bl = ~0ULL;
#pragma unroll
            for (int j = 0; j < 4; ++j) {
                const int c = col0 + wc + j * 16 + ln;
                u64 key = (float_key(acc[i][j][reg]) << 32) | (unsigned int)c;
                if (c != lab && key < bl) bl = key;
            }
#pragma unroll
            for (int off = 1; off < 16; off <<= 1) {
                u64 o = shfl_xor_u64(bl, off);
                if (o < bl) bl = o;
            }
            if (ln == 0) sRedR[w & 1][lr] = bl;
        }
    }

    // col-wise argmin -> LDS (skip on diagonal: duplicate of row-pass)
    if (!diag) {
#pragma unroll
        for (int j = 0; j < 4; ++j) {
            const int cl  = wc + j * 16 + ln;
            const int lab = sLabC[cl];
            u64 bl = ~0ULL;
#pragma unroll
            for (int i = 0; i < 4; ++i) {
#pragma unroll
                for (int reg = 0; reg < 4; ++reg) {
                    const int rg = row0 + wr + i * 16 + qk * 4 + reg;
                    u64 key = (float_key(acc[i][j][reg]) << 32) | (unsigned int)rg;
                    if (rg != lab && key < bl) bl = key;
                }
            }
            u64 o = shfl_xor_u64(bl, 16); if (o < bl) bl = o;
            o     = shfl_xor_u64(bl, 32); if (o < bl) bl = o;
            if (qk == 0) sRedC[w >> 1][cl] = bl;
        }
    }

    __syncthreads();
    // exactly-once writes: row panel 'by' slot bx; col panel 'bx' slot by
    if (tid < 128) {
        u64 a = sRedR[0][tid], b = sRedR[1][tid];
        P[(size_t)(row0 + tid) * 32 + bx] = (a < b ? a : b);
    } else if (!diag) {
        const int c = tid - 128;
        u64 a = sRedC[0][c], b = sRedC[1][c];
        P[(size_t)(col0 + c) * 32 + by] = (a < b ? a : b);
    }
}

// one wave per row: min-reduce the 32 partial keys, then distances + relu
__global__ __launch_bounds__(256) void loss_kernel(
    const float* __restrict__ ftr, const float* __restrict__ proto,
    const int* __restrict__ label, const u64* __restrict__ P,
    float* __restrict__ out, int B, int D, float inv_b)
{
    const int gid  = blockIdx.x * blockDim.x + threadIdx.x;
    const int row  = gid >> 6;
    const int lane = gid & 63;
    if (row >= B) return;

    u64 bl = (lane < 32) ? P[(size_t)row * 32 + lane] : ~0ULL;
#pragma unroll
    for (int off = 16; off >= 1; off >>= 1) {
        u64 o = shfl_xor_u64(bl, off);
        if (o < bl) bl = o;
    }
    {   // merge across half-waves so ALL 64 lanes hold the true min
        u64 o = shfl_xor_u64(bl, 32);
        if (o < bl) bl = o;
    }
    const int neg = (int)(unsigned int)(bl & 0xFFFFFFFFULL);
    const int lab = label[row];

    float pd = 0.0f, nd = 0.0f;
    for (int d = lane * 4; d < D; d += 256) {
        float4 f = *(const float4*)(ftr   + (size_t)row * D + d);
        float4 y = *(const float4*)(proto + (size_t)lab * D + d);
        float4 n = *(const float4*)(ftr   + (size_t)neg * D + d);
        float dx = f.x - y.x, dy = f.y - y.y, dz = f.z - y.z, dw = f.w - y.w;
        pd += dx * dx + dy * dy + dz * dz + dw * dw;
        dx = f.x - n.x; dy = f.y - n.y; dz = f.z - n.z; dw = f.w - n.w;
        nd += dx * dx + dy * dy + dz * dz + dw * dw;
    }
#pragma unroll
    for (int off = 32; off >= 1; off >>= 1) {
        pd += __shfl_xor(pd, off, 64);
        nd += __shfl_xor(nd, off, 64);
    }
    if (lane == 0) {
        float l = pd - nd + 0.5f;
        if (l > 0.0f) atomicAdd(out, l * inv_b);
    }
}

extern "C" void kernel_launch(void* const* d_in, const int* in_sizes, int n_in,
                              void* d_out, int out_size, void* d_ws, size_t ws_size,
                              hipStream_t stream) {
    const float* ftr   = (const float*)d_in[0];
    // d_in[1] = teachor_ftr unused by the reference
    const float* proto = (const float*)d_in[2];
    const int*   label = (const int*)d_in[3];

    const int B = in_sizes[3];
    const int D = in_sizes[0] / B;      // 256

    // ws layout: P[B][32] u64 partial keys (1 MB) | F[B*D] f16 (2 MB)
    u64* P = (u64*)d_ws;
    size_t off = ((size_t)B * 32 * 8 + 255) & ~(size_t)255;
    f16* F = (f16*)((char*)d_ws + off);
    float* out = (float*)d_out;

    const int prep_threads = (B * D) >> 2;
    prep_kernel<<<(prep_threads + 255) / 256, 256, 0, stream>>>(ftr, F, out, B, D);

    const int nb   = B / 128;
    const int ntri = nb * (nb + 1) / 2;
    sim_kernel<<<ntri, 256, 0, stream>>>(F, label, P, B, D);

    loss_kernel<<<(B * 64 + 255) / 256, 256, 0, stream>>>(ftr, proto, label, P, out, B, D,
                                                          1.0f / (float)B);
}